// Round 12
// baseline (51.478 us; speedup 1.0000x reference)
//
#include <hip/hip_runtime.h>

#define EPSF 1e-7f

typedef unsigned int u32;
typedef _Float16 h2_t __attribute__((ext_vector_type(2)));

// ---- DPP cross-lane helpers (VALU pipe, no DS, verified R2-R8) ----
#define DPPF0(x, ctrl) \
    __int_as_float(__builtin_amdgcn_update_dpp(0, __float_as_int(x), ctrl, 0xF, 0xF, false))

__device__ __forceinline__ float f_rcp(float x) { return __builtin_amdgcn_rcpf(x); }
__device__ __forceinline__ float wave_shr1_f(float x) { return DPPF0(x, 0x138); }

__device__ __forceinline__ float wave_max64(float x) {
    x = fmaxf(x, DPPF0(x, 0x111));   // row_shr:1
    x = fmaxf(x, DPPF0(x, 0x112));   // row_shr:2
    x = fmaxf(x, DPPF0(x, 0x114));   // row_shr:4
    x = fmaxf(x, DPPF0(x, 0x118));   // row_shr:8
    x = fmaxf(x, DPPF0(x, 0x142));   // row_bcast:15
    x = fmaxf(x, DPPF0(x, 0x143));   // row_bcast:31
    return __int_as_float(__builtin_amdgcn_readlane(__float_as_int(x), 63));
}

__device__ __forceinline__ float wave_sum64(float x) {
    x += DPPF0(x, 0x111);
    x += DPPF0(x, 0x112);
    x += DPPF0(x, 0x114);
    x += DPPF0(x, 0x118);
    x += DPPF0(x, 0x142);
    x += DPPF0(x, 0x143);
    return __int_as_float(__builtin_amdgcn_readlane(__float_as_int(x), 63));
}

// ---- one CTC step, q-normalized (R4-verified math), fp16 label pair ----
// u_s' = (u_s + u_{s-1} + skip*u_{s-2}) * q_s ; blank states: q == 1.
#define STEPQ(PW_, PBE_) do { \
    const h2_t h_ = __builtin_bit_cast(h2_t, PW_); \
    const float rpb_ = f_rcp(PBE_); \
    const float q1 = ((float)h_.x + EPSF) * rpb_; \
    const float q3 = ((float)h_.y + EPSF) * rpb_; \
    const float n3 = wave_shr1_f(u3); \
    const float t1 = fmaf(m1, n3, u0 + u1); \
    const float t3 = fmaf(m3, u1, u2 + u3); \
    u4 = u4 + u3; \
    u3 = t3 * q3; \
    u2 = u2 + u1; \
    u1 = t1 * q1; \
    u0 = u0 + n3; \
} while (0)

#define SNAP2(RM, LM) do { \
    float mm_ = fmaxf(fmaxf(u0, u1), fmaxf(u2, fmaxf(u3, u4))); \
    mm_ = wave_max64(mm_); \
    RM = f_rcp(mm_); \
    LM = __logf(mm_); \
} while (0)

#define APPLY2(RM, LM) do { \
    u0 *= RM; u1 *= RM; u2 *= RM; u3 *= RM; u4 *= RM; \
    O += LM; \
} while (0)

// load window (8 rows) from LDS into named registers (static indexing)
#define LDW(X, BASE) do { \
    X##k0 = pkl[(BASE) + 0][lane]; X##k1 = pkl[(BASE) + 1][lane]; \
    X##k2 = pkl[(BASE) + 2][lane]; X##k3 = pkl[(BASE) + 3][lane]; \
    X##k4 = pkl[(BASE) + 4][lane]; X##k5 = pkl[(BASE) + 5][lane]; \
    X##k6 = pkl[(BASE) + 6][lane]; X##k7 = pkl[(BASE) + 7][lane]; \
    X##b0 = pbl[(BASE) + 0]; X##b1 = pbl[(BASE) + 1]; \
    X##b2 = pbl[(BASE) + 2]; X##b3 = pbl[(BASE) + 3]; \
    X##b4 = pbl[(BASE) + 4]; X##b5 = pbl[(BASE) + 5]; \
    X##b6 = pbl[(BASE) + 6]; X##b7 = pbl[(BASE) + 7]; \
} while (0)

// full window, R4 cadence: apply@2 (prev snap), snap@4, apply@6, snap@8
#define CONS8W(X) do { \
    STEPQ(X##k0, X##b0 + EPSF); STEPQ(X##k1, X##b1 + EPSF); APPLY2(rmA, lmA); \
    STEPQ(X##k2, X##b2 + EPSF); STEPQ(X##k3, X##b3 + EPSF); SNAP2(rmB, lmB); \
    STEPQ(X##k4, X##b4 + EPSF); STEPQ(X##k5, X##b5 + EPSF); APPLY2(rmB, lmB); \
    STEPQ(X##k6, X##b6 + EPSF); STEPQ(X##k7, X##b7 + EPSF); SNAP2(rmA, lmA); \
} while (0)

// window 0: rows 1..7 (row 0 is the init), same bounded cadence
#define CONS0W(X) do { \
    STEPQ(X##k1, X##b1 + EPSF); STEPQ(X##k2, X##b2 + EPSF); APPLY2(rmA, lmA); \
    STEPQ(X##k3, X##b3 + EPSF); STEPQ(X##k4, X##b4 + EPSF); SNAP2(rmB, lmB); \
    STEPQ(X##k5, X##b5 + EPSF); STEPQ(X##k6, X##b6 + EPSF); APPLY2(rmB, lmB); \
    STEPQ(X##k7, X##b7 + EPSF); SNAP2(rmA, lmA); \
} while (0)

// =====================================================================
// Fused kernel, T=512/C=128/U=128. One block (4 waves) per batch row.
// Phase 1 (all 4 waves): gather label probs -> LDS half2 pkl[512][64],
//   blank column -> fp32 pbl[512]. One __syncthreads.
// Phase 2 (wave 0): 511-step scan from LDS. Lane l owns states 4l..4l+3
//   (+256 on lane 63). Conflict-free lane-linear LDS reads, +1-window
//   register double buffer. No inline asm anywhere.
// =====================================================================
__global__ __launch_bounds__(256, 1) void ctc_fused512(
        const int* __restrict__ y_true, const float* __restrict__ y_pred,
        float* __restrict__ out) {
    __shared__ u32   pkl[512][64];   // 128 KB: half2(p[c1],p[c3]) per (t,lane)
    __shared__ float pbl[512];       // 2 KB: blank prob per row

    const int b    = blockIdx.x;
    const int tid  = threadIdx.x;
    const int w    = tid >> 6;
    const int lane = tid & 63;
    const float* __restrict__ yp = y_pred + (size_t)b * (512 * 128);

    const int2 lc = ((const int2*)(y_true + (size_t)b * 128))[lane];
    const int c1 = lc.x, c3 = lc.y;

    // ---- phase 1: pack. wave w covers rows [w*128, (w+1)*128) ----
    {
        const int t0 = w * 128;
        const float* __restrict__ rp = yp + (size_t)t0 * 128;
#pragma unroll 8
        for (int r = 0; r < 128; ++r) {
            const float p1 = rp[r * 128 + c1];
            const float p3 = rp[r * 128 + c3];
            const u32 wd = (u32)__builtin_bit_cast(unsigned short, (_Float16)p1)
                         | ((u32)__builtin_bit_cast(unsigned short, (_Float16)p3) << 16);
            pkl[t0 + r][lane] = wd;
        }
        pbl[t0 + lane]      = rp[(size_t)lane * 128 + 127];
        pbl[t0 + 64 + lane] = rp[(size_t)(64 + lane) * 128 + 127];
    }
    __syncthreads();
    if (w != 0) return;

    // ---- phase 2: scan (wave 0 only) ----
    const int cp = __builtin_amdgcn_update_dpp(0, c3, 0x138, 0xF, 0xF, false);
    const float m1 = (lane > 0 && c1 != cp) ? 1.f : 0.f;
    const float m3 = (c3 != c1) ? 1.f : 0.f;

    // blank log-sum over rows 1..511 (scan-independent, vectorized)
    float bls = 0.f;
#pragma unroll
    for (int k = 0; k < 8; ++k) {
        const int t = lane * 8 + k;
        if (t >= 1) bls += __logf(pbl[t] + EPSF);
    }
    bls = wave_sum64(bls);

    // init from row 0 (exact fp32 from global)
    float u0, u1, u2 = 0.f, u3 = 0.f, u4 = 0.f;
    u0 = (lane == 0) ? yp[127] + EPSF : 0.f;
    u1 = (lane == 0) ? yp[c1] + EPSF : 0.f;
    float O = 0.f;
    float rmA = 1.0f, lmA = 0.0f, rmB = 1.0f, lmB = 0.0f;

    u32 Ak0, Ak1, Ak2, Ak3, Ak4, Ak5, Ak6, Ak7;
    u32 Bk0, Bk1, Bk2, Bk3, Bk4, Bk5, Bk6, Bk7;
    float Ab0, Ab1, Ab2, Ab3, Ab4, Ab5, Ab6, Ab7;
    float Bb0, Bb1, Bb2, Bb3, Bb4, Bb5, Bb6, Bb7;

    LDW(A, 0);                       // W0 (rows 0..7)
    LDW(B, 8);                       // W1 prefetch
    CONS0W(A);                       // steps: rows 1..7

    // windows 1..62 in pairs; W(2j+1) consumed while W(2j+2) prefetched
    for (int j = 0; j < 31; ++j) {
        LDW(A, 16 * j + 16); CONS8W(B);   // consume W(2j+1), prefetch W(2j+2)
        LDW(B, 16 * j + 24); CONS8W(A);   // consume W(2j+2), prefetch W(2j+3)
    }
    CONS8W(B);                       // W63 (rows 504..511)

    // loss = -(snap-logs + blank-logsum + log(u[255] + u[256]))
    if (lane == 63) out[b] = -(O + bls + __logf(u3 + u4));
}

// =====================================================================
// Generic fallback (other shapes), R4-style q-form, immediate renorm.
// =====================================================================
__global__ __launch_bounds__(64, 1) void ctc_scan_generic(
        const int* __restrict__ y_true, const float* __restrict__ y_pred,
        float* __restrict__ out, int T, int C, int U) {
    const int b    = blockIdx.x;
    const int lane = threadIdx.x;
    const int blank = C - 1;
    const float* __restrict__ yp = y_pred + (size_t)b * T * C;

    const int2 lc = ((const int2*)(y_true + (size_t)b * U))[lane];
    const int c1 = lc.x, c3 = lc.y;
    const int cp = __builtin_amdgcn_update_dpp(0, c3, 0x138, 0xF, 0xF, false);
    const float m1 = (lane > 0 && c1 != cp) ? 1.f : 0.f;
    const float m3 = (c3 != c1) ? 1.f : 0.f;

    float u0, u1, u2 = 0.f, u3 = 0.f, u4 = 0.f;
    u0 = (lane == 0) ? yp[blank] + EPSF : 0.f;
    u1 = (lane == 0) ? yp[c1] + EPSF : 0.f;
    float O = 0.f;
    float rmA = 1.0f, lmA = 0.0f;
    int kren = 0;

    for (int t = 1; t < T; ++t) {
        const float* row = yp + (size_t)t * C;
        const float pbe = row[blank] + EPSF;
        const float rpb = f_rcp(pbe);
        const float q1  = (row[c1] + EPSF) * rpb;
        const float q3  = (row[c3] + EPSF) * rpb;
        const float n3  = wave_shr1_f(u3);
        const float t1  = fmaf(m1, n3, u0 + u1);
        const float t3  = fmaf(m3, u1, u2 + u3);
        u4 = u4 + u3;
        u3 = t3 * q3;
        u2 = u2 + u1;
        u1 = t1 * q1;
        u0 = u0 + n3;
        O += __logf(pbe);
        if (++kren == 4) { SNAP2(rmA, lmA); APPLY2(rmA, lmA); kren = 0; }
    }
    if (lane == 63) out[b] = -(O + __logf(u3 + u4));
}

extern "C" void kernel_launch(void* const* d_in, const int* in_sizes, int n_in,
                              void* d_out, int out_size, void* d_ws, size_t ws_size,
                              hipStream_t stream) {
    const int*   y_true = (const int*)d_in[0];
    const float* y_pred = (const float*)d_in[1];
    float*       out    = (float*)d_out;

    const int B = out_size;                 // 256
    const int U = in_sizes[0] / B;          // 128
    const int C = 128;                      // classes incl. blank
    const int T = in_sizes[1] / (B * C);    // 512

    if (T == 512 && C == 128 && U == 128) {
        ctc_fused512<<<B, 256, 0, stream>>>(y_true, y_pred, out);
    } else {
        ctc_scan_generic<<<B, 64, 0, stream>>>(y_true, y_pred, out, T, C, U);
    }
}